// Round 9
// baseline (256.509 us; speedup 1.0000x reference)
//
#include <hip/hip_runtime.h>

// 3x3 SAME conv + bias + ReLU, N=32, Cin=Cout=256, H=W=56, fp32 in/out.
// v9 = v7 with A (weights) moved out of LDS:
//  - Weights repacked to MFMA-fragment-major bf16: wf[(g*36+s)*2+ks][lane][16B];
//    each A-frag is one coalesced global_load_dwordx4 (1KB/wave, L2-resident),
//    double-buffered in registers, prefetched one K-step ahead.
//  - B (x_t NHWC bf16) staged via async global_load_lds w=16, pre-swizzled
//    per-lane GLOBAL source, linear LDS dest (v7 path, 0 conflicts).
//  - BM=128co x BN=128px, 4 waves, wave tile 64x64 (m4,n4), BK=64, 36 steps,
//    2-phase LDS double-buffer for B only (2x16KB), 1 barrier/step.

#define GLOBAL_AS __attribute__((address_space(1)))
#define LDS_AS __attribute__((address_space(3)))

typedef __attribute__((ext_vector_type(8))) short short8;
typedef __attribute__((ext_vector_type(4))) float f32x4;
typedef __attribute__((ext_vector_type(4))) unsigned int u32x4;

#define CIN   256
#define HWS   3136        // 56*56
#define PTOT  100352      // 32*3136
#define KTOT  2304        // CIN*9
#define ZPOFF 1179648     // 512B zero page
#define XTOFF 1310720     // x_t: PTOT*512 bytes
#define WSNEED (XTOFF + (size_t)PTOT * 512)

__device__ __forceinline__ unsigned short f2bf(float f) {
  unsigned u = __builtin_bit_cast(unsigned, f);
  return (unsigned short)((u + 0x7fffu + ((u >> 16) & 1u)) >> 16);  // RNE
}

// Weights OIHW fp32 -> bf16 fragment-major:
// wf16B[((g*36 + s)*2 + ks)*64 + lane], lane=(kq*16+rl): covers
// co = g*16+rl, ci = (s/9)*64 + ks*32 + kq*8 + j, tap = s%9.
__global__ void wcvt_kernel(const float* __restrict__ w, unsigned char* __restrict__ ws) {
  if (blockIdx.x == 0 && threadIdx.x < 128)
    ((unsigned*)(ws + ZPOFF))[threadIdx.x] = 0u;
  const int tid = blockIdx.x * 256 + threadIdx.x;   // 0..73727
  const int l   = tid & 63;
  const int fi  = tid >> 6;          // (g*36+s)*2+ks, 0..1151
  const int ks  = fi & 1;
  const int t2  = fi >> 1;
  const int g   = t2 / 36;
  const int s   = t2 - g * 36;
  const int cq  = s / 9;
  const int tap = s - cq * 9;
  const int rl  = l & 15;
  const int kq  = l >> 4;
  const int co  = g * 16 + rl;
  const int ci0 = cq * 64 + ks * 32 + kq * 8;
  const float* src = w + (size_t)co * KTOT + tap;
  u32x4 v;
#pragma unroll
  for (int j = 0; j < 4; ++j) {
    unsigned lo = f2bf(src[(size_t)(ci0 + 2 * j) * 9]);
    unsigned hi = f2bf(src[(size_t)(ci0 + 2 * j + 1) * 9]);
    v[j] = lo | (hi << 16);
  }
  *(u32x4*)(ws + (size_t)tid * 16) = v;
}

// x NCHW fp32 -> x_t [pix_global][256ci] bf16 (NHWC), via LDS transpose.
__global__ __launch_bounds__(256) void xcvt_kernel(const float* __restrict__ x,
                                                   unsigned char* __restrict__ ws) {
  __shared__ float lt[64 * 257];
  const int pg0 = blockIdx.x * 64;       // 64-px tile, never crosses images
  const int n   = pg0 / HWS;
  const int pi0 = pg0 - n * HWS;
  const int t   = threadIdx.x;
  {
    const int px = t & 63;
    const int cg = t >> 6;               // 0..3 (wave-uniform)
    const float* xb = x + ((size_t)n * 256) * HWS + pi0 + px;
#pragma unroll 8
    for (int i = 0; i < 64; ++i) {
      const int c = i * 4 + cg;
      lt[px * 257 + c] = xb[(size_t)c * HWS];
    }
  }
  __syncthreads();
  {
    const int slot = t & 31;             // 16B slot = 8 channels (32 slots/row)
    const int pxw  = t >> 5;             // 0..7
    unsigned char* xt = ws + XTOFF;
#pragma unroll
    for (int i = 0; i < 8; ++i) {
      const int p = i * 8 + pxw;
      const float* r = &lt[p * 257 + slot * 8];
      u32x4 v;
#pragma unroll
      for (int j = 0; j < 4; ++j)
        v[j] = (unsigned)f2bf(r[2 * j]) | ((unsigned)f2bf(r[2 * j + 1]) << 16);
      *(u32x4*)(xt + (size_t)(pg0 + p) * 512 + slot * 16) = v;
    }
  }
}

__global__ __launch_bounds__(256, 2) void conv_kernel(
    const unsigned char* __restrict__ ws, const float* __restrict__ bias,
    float* __restrict__ out) {
  // LDS: B double buffer, 2 x 16KB.
  __shared__ __align__(16) unsigned char smem[32768];

  const unsigned char* wf = ws;
  const unsigned char* xt = ws + XTOFF;
  const unsigned char* zp = ws + ZPOFF;

  const int bid = blockIdx.x;
  const int sw  = (bid & 7) * 196 + (bid >> 3);  // XCD-chunked, bijective (1568=8*196)
  const int co0 = (sw & 1) * 128;
  const int p0  = (sw >> 1) * 128;               // global pixel base

  const int t    = threadIdx.x;
  const int lane = t & 63;
  const int wave = t >> 6;     // 0..3
  const int wm   = wave & 1;   // co 64-half
  const int wn   = wave >> 1;  // px 64-half
  const int rl   = lane & 15;
  const int kq   = lane >> 4;
  const int l7   = lane & 7;
  const int l8   = lane >> 3;

  // ---- A: fragment-major global base pointers (coalesced 1KB/wave loads) ----
  const unsigned char* aW[4];
#pragma unroll
  for (int mi = 0; mi < 4; ++mi) {
    const int g = (co0 >> 4) + wm * 4 + mi;      // co group (16 rows)
    aW[mi] = wf + (size_t)g * 73728 + (size_t)lane * 16;
  }

  // ---- B staging lane precompute (v7 path) ----
  const unsigned chanoff = (unsigned)((l7 * 16) ^ ((l8 & 7) << 4));
  long long bG[4];
  int hB[4], wB[4];
#pragma unroll
  for (int i = 0; i < 4; ++i) {
    const int row = wave * 32 + i * 8 + l8;       // 0..127 (px row)
    const int pg = p0 + row;
    const int n  = pg / HWS;
    const int pi = pg - n * HWS;
    hB[i] = pi / 56;
    wB[i] = pi - hB[i] * 56;
    bG[i] = (long long)pg * 512 + (long long)chanoff;
  }

  f32x4 acc[4][4];
  const f32x4 zero4 = {0.f, 0.f, 0.f, 0.f};
#pragma unroll
  for (int mi = 0; mi < 4; ++mi)
#pragma unroll
    for (int ni = 0; ni < 4; ++ni) acc[mi][ni] = zero4;

  auto stage = [&](int s, int buf) {
    const int cq  = s / 9;
    const int tap = s - cq * 9;
    const int kh  = tap / 3;
    const int dh  = kh - 1;
    const int dw  = (tap - kh * 3) - 1;
    unsigned char* lb = smem + buf * 16384;
    const long long doff = (long long)(dh * 56 + dw) * 512 + cq * 128;
#pragma unroll
    for (int i = 0; i < 4; ++i) {
      const int hh  = hB[i] + dh;
      const int wwi = wB[i] + dw;
      const bool ok = ((unsigned)hh < 56u) && ((unsigned)wwi < 56u);
      const unsigned char* g = ok ? (xt + bG[i] + doff) : zp;
      __builtin_amdgcn_global_load_lds(
          (const GLOBAL_AS unsigned int*)g,
          (LDS_AS unsigned int*)(lb + (wave * 4 + i) * 1024), 16, 0, 0);
    }
  };

  auto aload = [&](int s, short8* dst) {
#pragma unroll
    for (int ks = 0; ks < 2; ++ks)
#pragma unroll
      for (int mi = 0; mi < 4; ++mi)
        dst[ks * 4 + mi] =
            *(const short8*)(aW[mi] + (unsigned)((s * 2 + ks) * 1024));
  };

  // compute-phase B read offsets (v7): row (wn*64+ni*16+rl), 128B rows,
  // byte (kq*16 + ks*64) ^ ((row&7)<<4); row&7 == rl&7 == l7.
  unsigned offB[2];
#pragma unroll
  for (int ks = 0; ks < 2; ++ks)
    offB[ks] = (unsigned)((wn * 64 + rl) * 128) +
               (unsigned)((kq * 16 + ks * 64) ^ (l7 << 4));

  auto compute = [&](int buf, const short8* av) {
    const unsigned char* bB = smem + buf * 16384;
#pragma unroll
    for (int ks = 0; ks < 2; ++ks) {
      short8 bv[4];
#pragma unroll
      for (int ni = 0; ni < 4; ++ni)
        bv[ni] = *(const short8*)(bB + offB[ks] + ni * 2048);
#pragma unroll
      for (int mi = 0; mi < 4; ++mi)
#pragma unroll
        for (int ni = 0; ni < 4; ++ni)
          acc[mi][ni] = __builtin_amdgcn_mfma_f32_16x16x32_bf16(
              av[ks * 4 + mi], bv[ni], acc[mi][ni], 0, 0, 0);
    }
  };

  // ---- pipeline: B LDS dbuf + A register dbuf, 36 K-steps ----
  short8 aregA[8], aregB[8];
  aload(0, aregA);
  stage(0, 0);
  __syncthreads();
#pragma unroll 1
  for (int qq = 0; qq < 18; ++qq) {
    const int s = qq * 2;
    stage(s + 1, 1);
    aload(s + 1, aregB);
    compute(0, aregA);
    __syncthreads();
    if (s + 2 < 36) {
      stage(s + 2, 0);
      aload(s + 2, aregA);
    }
    compute(1, aregB);
    __syncthreads();
  }

  // ---- epilogue: bias + ReLU. C/D: col=lane&15, row=(lane>>4)*4+j ----
#pragma unroll
  for (int mi = 0; mi < 4; ++mi) {
    const int row = co0 + wm * 64 + mi * 16 + kq * 4;
    float br[4];
#pragma unroll
    for (int j = 0; j < 4; ++j) br[j] = bias[row + j];
#pragma unroll
    for (int ni = 0; ni < 4; ++ni) {
      const int pgb = p0 + wn * 64 + ni * 16;     // 16-span within one image
      const int n   = pgb / HWS;
      const int pib = pgb - n * HWS;
#pragma unroll
      for (int j = 0; j < 4; ++j) {
        float v = acc[mi][ni][j] + br[j];
        out[(size_t)(n * 256 + row + j) * HWS + pib + rl] = fmaxf(v, 0.f);
      }
    }
  }
}

// Correct-but-slow fallback if workspace is too small (not expected).
__global__ void naive_kernel(const float* __restrict__ x, const float* __restrict__ w,
                             const float* __restrict__ bias, float* __restrict__ out) {
  int idx = blockIdx.x * 256 + threadIdx.x;
  if (idx >= 32 * 256 * HWS) return;
  int n  = idx / (256 * HWS);
  int r  = idx - n * 256 * HWS;
  int co = r / HWS;
  int p  = r - co * HWS;
  int h = p / 56, ww = p - h * 56;
  float s = bias[co];
  const float* xb = x + (size_t)n * 256 * HWS;
  const float* wbp = w + (size_t)co * KTOT;
  for (int ci = 0; ci < 256; ++ci) {
    const float* xc = xb + (size_t)ci * HWS;
    const float* wc = wbp + ci * 9;
    for (int kh = 0; kh < 3; ++kh) {
      int hh = h + kh - 1;
      if ((unsigned)hh >= 56u) continue;
      for (int kw = 0; kw < 3; ++kw) {
        int w2 = ww + kw - 1;
        if ((unsigned)w2 >= 56u) continue;
        s += xc[hh * 56 + w2] * wc[kh * 3 + kw];
      }
    }
  }
  out[idx] = fmaxf(s, 0.f);
}

extern "C" void kernel_launch(void* const* d_in, const int* in_sizes, int n_in,
                              void* d_out, int out_size, void* d_ws, size_t ws_size,
                              hipStream_t stream) {
  const float* x    = (const float*)d_in[0];
  const float* w    = (const float*)d_in[1];
  const float* bias = (const float*)d_in[2];
  float* out        = (float*)d_out;

  if (ws_size < WSNEED) {
    hipLaunchKernelGGL(naive_kernel, dim3((32 * 256 * HWS + 255) / 256), dim3(256),
                       0, stream, x, w, bias, out);
    return;
  }
  unsigned char* ws = (unsigned char*)d_ws;
  hipLaunchKernelGGL(wcvt_kernel, dim3(288), dim3(256), 0, stream, w, ws);
  hipLaunchKernelGGL(xcvt_kernel, dim3(PTOT / 64), dim3(256), 0, stream, x, ws);
  hipLaunchKernelGGL(conv_kernel, dim3(1568), dim3(256), 0, stream, ws, bias, out);
}

// Round 10
// 184.231 us; speedup vs baseline: 1.3923x; 1.3923x over previous
//
#include <hip/hip_runtime.h>

// 3x3 SAME conv + bias + ReLU, N=32, Cin=Cout=256, H=W=56, fp32 in/out.
// v10 = v9 + sched_barrier(0) pinning the A-register prefetch:
//  - Weights repacked to MFMA-fragment-major bf16; each A-frag is one
//    coalesced global_load_dwordx4 (1KB/wave, L2-resident), double-buffered
//    in registers, prefetched one K-step ahead. sched_barrier(0) between
//    the prefetch issue and the compute phase stops the compiler from
//    sinking the loads to their use sites (v9's failure: VGPR=92 showed
//    the buffers were never live).
//  - B (x_t NHWC bf16) staged via async global_load_lds w=16, pre-swizzled
//    per-lane GLOBAL source, linear LDS dest (v7 path, 0 conflicts).
//  - BM=128co x BN=128px, 4 waves, wave tile 64x64 (m4,n4), BK=64, 36 steps,
//    B-only LDS double buffer (2x16KB), 1 barrier/step.

#define GLOBAL_AS __attribute__((address_space(1)))
#define LDS_AS __attribute__((address_space(3)))

typedef __attribute__((ext_vector_type(8))) short short8;
typedef __attribute__((ext_vector_type(4))) float f32x4;
typedef __attribute__((ext_vector_type(4))) unsigned int u32x4;

#define CIN   256
#define HWS   3136        // 56*56
#define PTOT  100352      // 32*3136
#define KTOT  2304        // CIN*9
#define ZPOFF 1179648     // 512B zero page
#define XTOFF 1310720     // x_t: PTOT*512 bytes
#define WSNEED (XTOFF + (size_t)PTOT * 512)

__device__ __forceinline__ unsigned short f2bf(float f) {
  unsigned u = __builtin_bit_cast(unsigned, f);
  return (unsigned short)((u + 0x7fffu + ((u >> 16) & 1u)) >> 16);  // RNE
}

// Weights OIHW fp32 -> bf16 fragment-major:
// wf16B[((g*36 + s)*2 + ks)*64 + lane], lane=(kq*16+rl): covers
// co = g*16+rl, ci = (s/9)*64 + ks*32 + kq*8 + j, tap = s%9.
__global__ void wcvt_kernel(const float* __restrict__ w, unsigned char* __restrict__ ws) {
  if (blockIdx.x == 0 && threadIdx.x < 128)
    ((unsigned*)(ws + ZPOFF))[threadIdx.x] = 0u;
  const int tid = blockIdx.x * 256 + threadIdx.x;   // 0..73727
  const int l   = tid & 63;
  const int fi  = tid >> 6;          // (g*36+s)*2+ks, 0..1151
  const int ks  = fi & 1;
  const int t2  = fi >> 1;
  const int g   = t2 / 36;
  const int s   = t2 - g * 36;
  const int cq  = s / 9;
  const int tap = s - cq * 9;
  const int rl  = l & 15;
  const int kq  = l >> 4;
  const int co  = g * 16 + rl;
  const int ci0 = cq * 64 + ks * 32 + kq * 8;
  const float* src = w + (size_t)co * KTOT + tap;
  u32x4 v;
#pragma unroll
  for (int j = 0; j < 4; ++j) {
    unsigned lo = f2bf(src[(size_t)(ci0 + 2 * j) * 9]);
    unsigned hi = f2bf(src[(size_t)(ci0 + 2 * j + 1) * 9]);
    v[j] = lo | (hi << 16);
  }
  *(u32x4*)(ws + (size_t)tid * 16) = v;
}

// x NCHW fp32 -> x_t [pix_global][256ci] bf16 (NHWC), via LDS transpose.
__global__ __launch_bounds__(256) void xcvt_kernel(const float* __restrict__ x,
                                                   unsigned char* __restrict__ ws) {
  __shared__ float lt[64 * 257];
  const int pg0 = blockIdx.x * 64;       // 64-px tile, never crosses images
  const int n   = pg0 / HWS;
  const int pi0 = pg0 - n * HWS;
  const int t   = threadIdx.x;
  {
    const int px = t & 63;
    const int cg = t >> 6;               // 0..3 (wave-uniform)
    const float* xb = x + ((size_t)n * 256) * HWS + pi0 + px;
#pragma unroll 8
    for (int i = 0; i < 64; ++i) {
      const int c = i * 4 + cg;
      lt[px * 257 + c] = xb[(size_t)c * HWS];
    }
  }
  __syncthreads();
  {
    const int slot = t & 31;             // 16B slot = 8 channels (32 slots/row)
    const int pxw  = t >> 5;             // 0..7
    unsigned char* xt = ws + XTOFF;
#pragma unroll
    for (int i = 0; i < 8; ++i) {
      const int p = i * 8 + pxw;
      const float* r = &lt[p * 257 + slot * 8];
      u32x4 v;
#pragma unroll
      for (int j = 0; j < 4; ++j)
        v[j] = (unsigned)f2bf(r[2 * j]) | ((unsigned)f2bf(r[2 * j + 1]) << 16);
      *(u32x4*)(xt + (size_t)(pg0 + p) * 512 + slot * 16) = v;
    }
  }
}

__global__ __launch_bounds__(256, 2) void conv_kernel(
    const unsigned char* __restrict__ ws, const float* __restrict__ bias,
    float* __restrict__ out) {
  // LDS: B double buffer, 2 x 16KB.
  __shared__ __align__(16) unsigned char smem[32768];

  const unsigned char* wf = ws;
  const unsigned char* xt = ws + XTOFF;
  const unsigned char* zp = ws + ZPOFF;

  const int bid = blockIdx.x;
  const int sw  = (bid & 7) * 196 + (bid >> 3);  // XCD-chunked, bijective (1568=8*196)
  const int co0 = (sw & 1) * 128;
  const int p0  = (sw >> 1) * 128;               // global pixel base

  const int t    = threadIdx.x;
  const int lane = t & 63;
  const int wave = t >> 6;     // 0..3
  const int wm   = wave & 1;   // co 64-half
  const int wn   = wave >> 1;  // px 64-half
  const int rl   = lane & 15;
  const int kq   = lane >> 4;
  const int l7   = lane & 7;
  const int l8   = lane >> 3;

  // ---- A: fragment-major global base pointers (coalesced 1KB/wave loads) ----
  const unsigned char* aW[4];
#pragma unroll
  for (int mi = 0; mi < 4; ++mi) {
    const int g = (co0 >> 4) + wm * 4 + mi;      // co group (16 rows)
    aW[mi] = wf + (size_t)g * 73728 + (size_t)lane * 16;
  }

  // ---- B staging lane precompute (v7 path) ----
  const unsigned chanoff = (unsigned)((l7 * 16) ^ ((l8 & 7) << 4));
  long long bG[4];
  int hB[4], wB[4];
#pragma unroll
  for (int i = 0; i < 4; ++i) {
    const int row = wave * 32 + i * 8 + l8;       // 0..127 (px row)
    const int pg = p0 + row;
    const int n  = pg / HWS;
    const int pi = pg - n * HWS;
    hB[i] = pi / 56;
    wB[i] = pi - hB[i] * 56;
    bG[i] = (long long)pg * 512 + (long long)chanoff;
  }

  f32x4 acc[4][4];
  const f32x4 zero4 = {0.f, 0.f, 0.f, 0.f};
#pragma unroll
  for (int mi = 0; mi < 4; ++mi)
#pragma unroll
    for (int ni = 0; ni < 4; ++ni) acc[mi][ni] = zero4;

  auto stage = [&](int s, int buf) {
    const int cq  = s / 9;
    const int tap = s - cq * 9;
    const int kh  = tap / 3;
    const int dh  = kh - 1;
    const int dw  = (tap - kh * 3) - 1;
    unsigned char* lb = smem + buf * 16384;
    const long long doff = (long long)(dh * 56 + dw) * 512 + cq * 128;
#pragma unroll
    for (int i = 0; i < 4; ++i) {
      const int hh  = hB[i] + dh;
      const int wwi = wB[i] + dw;
      const bool ok = ((unsigned)hh < 56u) && ((unsigned)wwi < 56u);
      const unsigned char* g = ok ? (xt + bG[i] + doff) : zp;
      __builtin_amdgcn_global_load_lds(
          (const GLOBAL_AS unsigned int*)g,
          (LDS_AS unsigned int*)(lb + (wave * 4 + i) * 1024), 16, 0, 0);
    }
  };

  auto aload = [&](int s, short8* dst) {
#pragma unroll
    for (int ks = 0; ks < 2; ++ks)
#pragma unroll
      for (int mi = 0; mi < 4; ++mi)
        dst[ks * 4 + mi] =
            *(const short8*)(aW[mi] + (unsigned)((s * 2 + ks) * 1024));
  };

  // compute-phase B read offsets (v7): row (wn*64+ni*16+rl), 128B rows,
  // byte (kq*16 + ks*64) ^ ((row&7)<<4); row&7 == rl&7 == l7.
  unsigned offB[2];
#pragma unroll
  for (int ks = 0; ks < 2; ++ks)
    offB[ks] = (unsigned)((wn * 64 + rl) * 128) +
               (unsigned)((kq * 16 + ks * 64) ^ (l7 << 4));

  auto compute = [&](int buf, const short8* av) {
    const unsigned char* bB = smem + buf * 16384;
#pragma unroll
    for (int ks = 0; ks < 2; ++ks) {
      short8 bv[4];
#pragma unroll
      for (int ni = 0; ni < 4; ++ni)
        bv[ni] = *(const short8*)(bB + offB[ks] + ni * 2048);
#pragma unroll
      for (int mi = 0; mi < 4; ++mi)
#pragma unroll
        for (int ni = 0; ni < 4; ++ni)
          acc[mi][ni] = __builtin_amdgcn_mfma_f32_16x16x32_bf16(
              av[ks * 4 + mi], bv[ni], acc[mi][ni], 0, 0, 0);
    }
  };

  // ---- pipeline: B LDS dbuf + A register dbuf (pinned), 36 K-steps ----
  short8 aregA[8], aregB[8];
  aload(0, aregA);
  stage(0, 0);
  __syncthreads();
#pragma unroll 1
  for (int qq = 0; qq < 18; ++qq) {
    const int s = qq * 2;
    // step s (even): compute from buf0/aregA, prefetch s+1 into buf1/aregB
    aload(s + 1, aregB);
    stage(s + 1, 1);
    __builtin_amdgcn_sched_barrier(0);   // pin prefetch issue before compute
    compute(0, aregA);
    __syncthreads();
    // step s+1 (odd): compute from buf1/aregB, prefetch s+2 into buf0/aregA
    if (s + 2 < 36) {
      aload(s + 2, aregA);
      stage(s + 2, 0);
    }
    __builtin_amdgcn_sched_barrier(0);
    compute(1, aregB);
    __syncthreads();
  }

  // ---- epilogue: bias + ReLU. C/D: col=lane&15, row=(lane>>4)*4+j ----
#pragma unroll
  for (int mi = 0; mi < 4; ++mi) {
    const int row = co0 + wm * 64 + mi * 16 + kq * 4;
    float br[4];
#pragma unroll
    for (int j = 0; j < 4; ++j) br[j] = bias[row + j];
#pragma unroll
    for (int ni = 0; ni < 4; ++ni) {
      const int pgb = p0 + wn * 64 + ni * 16;     // 16-span within one image
      const int n   = pgb / HWS;
      const int pib = pgb - n * HWS;
#pragma unroll
      for (int j = 0; j < 4; ++j) {
        float v = acc[mi][ni][j] + br[j];
        out[(size_t)(n * 256 + row + j) * HWS + pib + rl] = fmaxf(v, 0.f);
      }
    }
  }
}

// Correct-but-slow fallback if workspace is too small (not expected).
__global__ void naive_kernel(const float* __restrict__ x, const float* __restrict__ w,
                             const float* __restrict__ bias, float* __restrict__ out) {
  int idx = blockIdx.x * 256 + threadIdx.x;
  if (idx >= 32 * 256 * HWS) return;
  int n  = idx / (256 * HWS);
  int r  = idx - n * 256 * HWS;
  int co = r / HWS;
  int p  = r - co * HWS;
  int h = p / 56, ww = p - h * 56;
  float s = bias[co];
  const float* xb = x + (size_t)n * 256 * HWS;
  const float* wbp = w + (size_t)co * KTOT;
  for (int ci = 0; ci < 256; ++ci) {
    const float* xc = xb + (size_t)ci * HWS;
    const float* wc = wbp + ci * 9;
    for (int kh = 0; kh < 3; ++kh) {
      int hh = h + kh - 1;
      if ((unsigned)hh >= 56u) continue;
      for (int kw = 0; kw < 3; ++kw) {
        int w2 = ww + kw - 1;
        if ((unsigned)w2 >= 56u) continue;
        s += xc[hh * 56 + w2] * wc[kh * 3 + kw];
      }
    }
  }
  out[idx] = fmaxf(s, 0.f);
}

extern "C" void kernel_launch(void* const* d_in, const int* in_sizes, int n_in,
                              void* d_out, int out_size, void* d_ws, size_t ws_size,
                              hipStream_t stream) {
  const float* x    = (const float*)d_in[0];
  const float* w    = (const float*)d_in[1];
  const float* bias = (const float*)d_in[2];
  float* out        = (float*)d_out;

  if (ws_size < WSNEED) {
    hipLaunchKernelGGL(naive_kernel, dim3((32 * 256 * HWS + 255) / 256), dim3(256),
                       0, stream, x, w, bias, out);
    return;
  }
  unsigned char* ws = (unsigned char*)d_ws;
  hipLaunchKernelGGL(wcvt_kernel, dim3(288), dim3(256), 0, stream, w, ws);
  hipLaunchKernelGGL(xcvt_kernel, dim3(PTOT / 64), dim3(256), 0, stream, x, ws);
  hipLaunchKernelGGL(conv_kernel, dim3(1568), dim3(256), 0, stream, ws, bias, out);
}

// Round 11
// 163.472 us; speedup vs baseline: 1.5691x; 1.1270x over previous
//
#include <hip/hip_runtime.h>

// 3x3 SAME conv + bias + ReLU, N=32, Cin=Cout=256, H=W=56, fp32 in/out.
// v11: m201-style 256x256 8-wave structure:
//  - Block 256co x 256px, 512 thr / 8 waves (2M x 4N), wave tile 128x64
//    (8m x 4n frags of 16x16x32), acc 128 VGPR.
//  - LDS 2 x (A 32KB + B 32KB) = 128KB, 1 block/CU.
//  - Per K-tile: [vmcnt(0); s_barrier] THEN issue next tile's 8
//    global_load_lds (they stay in flight across the whole tile's compute),
//    then 4 x 16-MFMA clusters wrapped in setprio, B-frags reg-reused.
//  - x pre-transformed to NHWC bf16 (x_t[pix][ci]); w repacked
//    [co][tap*256+ci] bf16; zero-page for halo lanes; v7-verified
//    XOR-swizzle algebra throughout.

#define GLOBAL_AS __attribute__((address_space(1)))
#define LDS_AS __attribute__((address_space(3)))

typedef __attribute__((ext_vector_type(8))) short short8;
typedef __attribute__((ext_vector_type(4))) float f32x4;
typedef __attribute__((ext_vector_type(4))) unsigned int u32x4;

#define CIN   256
#define HWS   3136        // 56*56
#define PTOT  100352      // 32*3136
#define KTOT  2304        // CIN*9
#define WROWB 4608        // KTOT*2 bytes per weight row
#define ZPOFF 1179648     // 512B zero page
#define XTOFF 1310720     // x_t: PTOT*512 bytes
#define WSNEED (XTOFF + (size_t)PTOT * 512)

__device__ __forceinline__ unsigned short f2bf(float f) {
  unsigned u = __builtin_bit_cast(unsigned, f);
  return (unsigned short)((u + 0x7fffu + ((u >> 16) & 1u)) >> 16);  // RNE
}

// Weights OIHW fp32 -> bf16 [co][tap*256+ci]; also zero the zero-page.
__global__ void wcvt_kernel(const float* __restrict__ w, unsigned char* __restrict__ ws) {
  if (blockIdx.x == 0 && threadIdx.x < 128)
    ((unsigned*)(ws + ZPOFF))[threadIdx.x] = 0u;
  int o = blockIdx.x * 256 + threadIdx.x;
  int co = o / KTOT;
  int rr = o - co * KTOT;
  int tap = rr >> 8;
  int ci = rr & 255;
  ((unsigned short*)ws)[o] = f2bf(w[co * KTOT + ci * 9 + tap]);
}

// x NCHW fp32 -> x_t [pix_global][256ci] bf16 (NHWC), via LDS transpose.
__global__ __launch_bounds__(256) void xcvt_kernel(const float* __restrict__ x,
                                                   unsigned char* __restrict__ ws) {
  __shared__ float lt[64 * 257];
  const int pg0 = blockIdx.x * 64;       // 64-px tile, never crosses images
  const int n   = pg0 / HWS;
  const int pi0 = pg0 - n * HWS;
  const int t   = threadIdx.x;
  {
    const int px = t & 63;
    const int cg = t >> 6;               // 0..3 (wave-uniform)
    const float* xb = x + ((size_t)n * 256) * HWS + pi0 + px;
#pragma unroll 8
    for (int i = 0; i < 64; ++i) {
      const int c = i * 4 + cg;
      lt[px * 257 + c] = xb[(size_t)c * HWS];
    }
  }
  __syncthreads();
  {
    const int slot = t & 31;             // 16B slot = 8 channels (32 slots/row)
    const int pxw  = t >> 5;             // 0..7
    unsigned char* xt = ws + XTOFF;
#pragma unroll
    for (int i = 0; i < 8; ++i) {
      const int p = i * 8 + pxw;
      const float* r = &lt[p * 257 + slot * 8];
      u32x4 v;
#pragma unroll
      for (int j = 0; j < 4; ++j)
        v[j] = (unsigned)f2bf(r[2 * j]) | ((unsigned)f2bf(r[2 * j + 1]) << 16);
      *(u32x4*)(xt + (size_t)(pg0 + p) * 512 + slot * 16) = v;
    }
  }
}

__global__ __launch_bounds__(512, 2) void conv_kernel(
    const unsigned char* __restrict__ ws, const float* __restrict__ bias,
    float* __restrict__ out) {
  // LDS: buf{0,1} x (A 32KB + B 32KB)
  __shared__ __align__(16) unsigned char smem[131072];

  const unsigned char* wb = ws;
  const unsigned char* xt = ws + XTOFF;
  const unsigned char* zp = ws + ZPOFF;

  const int bid = blockIdx.x;
  const int sw  = (bid & 7) * 49 + (bid >> 3);   // XCD-chunked, bijective (392=8*49)
  const int p0  = sw * 256;                      // global pixel base

  const int t    = threadIdx.x;
  const int lane = t & 63;
  const int wave = t >> 6;     // 0..7
  const int wm   = wave & 1;   // co half (128 rows)
  const int wn   = wave >> 1;  // px quarter (64 cols)
  const int rl   = lane & 15;
  const int kq   = lane >> 4;
  const int l7   = lane & 7;

  // ---- staging lane precompute: row = op*64 + (t>>3), slot = t&7 ----
  const int srow = t >> 3;                          // 0..63
  const unsigned swzs = (unsigned)(((t & 7) * 16) ^ ((srow & 7) << 4));
  const unsigned ldsW = (unsigned)(wave * 1024);    // wave-uniform chunk

  const unsigned char* aG[4];
  long long bG[4];
  int hB[4], wBp[4];
#pragma unroll
  for (int op = 0; op < 4; ++op) {
    const int arow = op * 64 + srow;                // co row 0..255
    aG[op] = wb + (size_t)arow * WROWB + swzs;
    const int pg = p0 + op * 64 + srow;             // px row 0..255
    const int n  = pg / HWS;
    const int pi = pg - n * HWS;
    hB[op]  = pi / 56;
    wBp[op] = pi - hB[op] * 56;
    bG[op]  = (long long)pg * 512 + (long long)swzs;
  }

  f32x4 acc[8][4];
  const f32x4 zero4 = {0.f, 0.f, 0.f, 0.f};
#pragma unroll
  for (int mi = 0; mi < 8; ++mi)
#pragma unroll
    for (int ni = 0; ni < 4; ++ni) acc[mi][ni] = zero4;

  auto stage = [&](int cq, int tap, int buf) {
    const int kh = tap / 3;
    const int dh = kh - 1;
    const int dw = (tap - kh * 3) - 1;
    const unsigned koffA = (unsigned)(tap * 512 + cq * 128);
    unsigned char* lb = smem + buf * 65536;
#pragma unroll
    for (int op = 0; op < 4; ++op)
      __builtin_amdgcn_global_load_lds(
          (const GLOBAL_AS unsigned int*)(aG[op] + koffA),
          (LDS_AS unsigned int*)(lb + op * 8192 + ldsW), 16, 0, 0);
    const long long doff = (long long)(dh * 56 + dw) * 512 + cq * 128;
#pragma unroll
    for (int op = 0; op < 4; ++op) {
      const int hh  = hB[op] + dh;
      const int wwi = wBp[op] + dw;
      const bool ok = ((unsigned)hh < 56u) && ((unsigned)wwi < 56u);
      const unsigned char* g = ok ? (xt + bG[op] + doff) : zp;
      __builtin_amdgcn_global_load_lds(
          (const GLOBAL_AS unsigned int*)g,
          (LDS_AS unsigned int*)(lb + 32768 + op * 8192 + ldsW), 16, 0, 0);
    }
  };

  // compute-phase per-lane offsets (128B rows, read XOR = store XOR)
  unsigned koff[2];
  koff[0] = (unsigned)((kq * 16) ^ (l7 << 4));
  koff[1] = (unsigned)((kq * 16 + 64) ^ (l7 << 4));
  unsigned offAm[8], offBn[4];
#pragma unroll
  for (int mi = 0; mi < 8; ++mi)
    offAm[mi] = (unsigned)((wm * 128 + mi * 16 + rl) * 128);
#pragma unroll
  for (int ni = 0; ni < 4; ++ni)
    offBn[ni] = (unsigned)((wn * 64 + ni * 16 + rl) * 128);

  // ---- prologue: stage tile 0 into buf0 ----
  stage(0, 0, 0);

  int buf = 0;
#pragma unroll 1
  for (int cq = 0; cq < 4; ++cq) {
#pragma unroll 1
    for (int tap = 0; tap < 9; ++tap) {
      // tile entry: wait own stage ops, then rendezvous (no drain of new ops)
      asm volatile("s_waitcnt vmcnt(0)\n\ts_barrier" ::: "memory");
      // issue next tile's 8 DMA ops - they stay in flight across this tile
      if (!((cq == 3) && (tap == 8))) {
        const int ntap = (tap == 8) ? 0 : tap + 1;
        const int ncq  = (tap == 8) ? cq + 1 : cq;
        stage(ncq, ntap, buf ^ 1);
      }
      const unsigned char* bA = smem + buf * 65536;
      const unsigned char* bB = bA + 32768;

      short8 bv[4], av[4];
      // ---- ks=0, m 0-3 ----
#pragma unroll
      for (int ni = 0; ni < 4; ++ni)
        bv[ni] = *(const short8*)(bB + offBn[ni] + koff[0]);
#pragma unroll
      for (int mi = 0; mi < 4; ++mi)
        av[mi] = *(const short8*)(bA + offAm[mi] + koff[0]);
      __builtin_amdgcn_s_setprio(1);
#pragma unroll
      for (int mi = 0; mi < 4; ++mi)
#pragma unroll
        for (int ni = 0; ni < 4; ++ni)
          acc[mi][ni] = __builtin_amdgcn_mfma_f32_16x16x32_bf16(
              av[mi], bv[ni], acc[mi][ni], 0, 0, 0);
      __builtin_amdgcn_s_setprio(0);
      // ---- ks=0, m 4-7 (B reused in regs) ----
#pragma unroll
      for (int mi = 0; mi < 4; ++mi)
        av[mi] = *(const short8*)(bA + offAm[mi + 4] + koff[0]);
      __builtin_amdgcn_s_setprio(1);
#pragma unroll
      for (int mi = 0; mi < 4; ++mi)
#pragma unroll
        for (int ni = 0; ni < 4; ++ni)
          acc[mi + 4][ni] = __builtin_amdgcn_mfma_f32_16x16x32_bf16(
              av[mi], bv[ni], acc[mi + 4][ni], 0, 0, 0);
      __builtin_amdgcn_s_setprio(0);
      // ---- ks=1, m 0-3 ----
#pragma unroll
      for (int ni = 0; ni < 4; ++ni)
        bv[ni] = *(const short8*)(bB + offBn[ni] + koff[1]);
#pragma unroll
      for (int mi = 0; mi < 4; ++mi)
        av[mi] = *(const short8*)(bA + offAm[mi] + koff[1]);
      __builtin_amdgcn_s_setprio(1);
#pragma unroll
      for (int mi = 0; mi < 4; ++mi)
#pragma unroll
        for (int ni = 0; ni < 4; ++ni)
          acc[mi][ni] = __builtin_amdgcn_mfma_f32_16x16x32_bf16(
              av[mi], bv[ni], acc[mi][ni], 0, 0, 0);
      __builtin_amdgcn_s_setprio(0);
      // ---- ks=1, m 4-7 ----
#pragma unroll
      for (int mi = 0; mi < 4; ++mi)
        av[mi] = *(const short8*)(bA + offAm[mi + 4] + koff[1]);
      __builtin_amdgcn_s_setprio(1);
#pragma unroll
      for (int mi = 0; mi < 4; ++mi)
#pragma unroll
        for (int ni = 0; ni < 4; ++ni)
          acc[mi + 4][ni] = __builtin_amdgcn_mfma_f32_16x16x32_bf16(
              av[mi], bv[ni], acc[mi + 4][ni], 0, 0, 0);
      __builtin_amdgcn_s_setprio(0);

      buf ^= 1;
    }
  }

  // ---- epilogue: bias + ReLU. C/D: col=lane&15, row=(lane>>4)*4+j ----
#pragma unroll
  for (int mi = 0; mi < 8; ++mi) {
    const int row = wm * 128 + mi * 16 + kq * 4;
    float br[4];
#pragma unroll
    for (int j = 0; j < 4; ++j) br[j] = bias[row + j];
#pragma unroll
    for (int ni = 0; ni < 4; ++ni) {
      const int pgb = p0 + wn * 64 + ni * 16;     // 16-span within one image
      const int n   = pgb / HWS;
      const int pib = pgb - n * HWS;
#pragma unroll
      for (int j = 0; j < 4; ++j) {
        float v = acc[mi][ni][j] + br[j];
        out[(size_t)(n * 256 + row + j) * HWS + pib + rl] = fmaxf(v, 0.f);
      }
    }
  }
}

// Correct-but-slow fallback if workspace is too small (not expected).
__global__ void naive_kernel(const float* __restrict__ x, const float* __restrict__ w,
                             const float* __restrict__ bias, float* __restrict__ out) {
  int idx = blockIdx.x * 256 + threadIdx.x;
  if (idx >= 32 * 256 * HWS) return;
  int n  = idx / (256 * HWS);
  int r  = idx - n * 256 * HWS;
  int co = r / HWS;
  int p  = r - co * HWS;
  int h = p / 56, ww = p - h * 56;
  float s = bias[co];
  const float* xb = x + (size_t)n * 256 * HWS;
  const float* wbp = w + (size_t)co * KTOT;
  for (int ci = 0; ci < 256; ++ci) {
    const float* xc = xb + (size_t)ci * HWS;
    const float* wc = wbp + ci * 9;
    for (int kh = 0; kh < 3; ++kh) {
      int hh = h + kh - 1;
      if ((unsigned)hh >= 56u) continue;
      for (int kw = 0; kw < 3; ++kw) {
        int w2 = ww + kw - 1;
        if ((unsigned)w2 >= 56u) continue;
        s += xc[hh * 56 + w2] * wc[kh * 3 + kw];
      }
    }
  }
  out[idx] = fmaxf(s, 0.f);
}

extern "C" void kernel_launch(void* const* d_in, const int* in_sizes, int n_in,
                              void* d_out, int out_size, void* d_ws, size_t ws_size,
                              hipStream_t stream) {
  const float* x    = (const float*)d_in[0];
  const float* w    = (const float*)d_in[1];
  const float* bias = (const float*)d_in[2];
  float* out        = (float*)d_out;

  if (ws_size < WSNEED) {
    hipLaunchKernelGGL(naive_kernel, dim3((32 * 256 * HWS + 255) / 256), dim3(256),
                       0, stream, x, w, bias, out);
    return;
  }
  unsigned char* ws = (unsigned char*)d_ws;
  hipLaunchKernelGGL(wcvt_kernel, dim3(2304), dim3(256), 0, stream, w, ws);
  hipLaunchKernelGGL(xcvt_kernel, dim3(PTOT / 64), dim3(256), 0, stream, x, ws);
  hipLaunchKernelGGL(conv_kernel, dim3(392), dim3(512), 0, stream, ws, bias, out);
}